// Round 3
// baseline (13237.163 us; speedup 1.0000x reference)
//
#include <hip/hip_runtime.h>
#include <stdint.h>
#include <stddef.h>

#define HH 256
#define WW 256
#define NCH 20
#define KH 128

// JAX threefry2x32 (20 rounds), exact.
__host__ __device__ inline void tf2x32(uint32_t k0, uint32_t k1,
                                       uint32_t x0, uint32_t x1,
                                       uint32_t* o0, uint32_t* o1) {
  uint32_t ks0 = k0, ks1 = k1, ks2 = k0 ^ k1 ^ 0x1BD11BDAu;
  x0 += ks0; x1 += ks1;
#define RND(r) { x0 += x1; x1 = (x1 << (r)) | (x1 >> (32 - (r))); x1 ^= x0; }
  RND(13) RND(15) RND(26) RND(6)   x0 += ks1; x1 += ks2 + 1u;
  RND(17) RND(29) RND(16) RND(24)  x0 += ks2; x1 += ks0 + 2u;
  RND(13) RND(15) RND(26) RND(6)   x0 += ks0; x1 += ks1 + 3u;
  RND(17) RND(29) RND(16) RND(24)  x0 += ks1; x1 += ks2 + 4u;
  RND(13) RND(15) RND(26) RND(6)   x0 += ks2; x1 += ks0 + 5u;
#undef RND
  *o0 = x0; *o1 = x1;
}

// One NCA step: xout = xin + S * chan_mask * (W2 @ relu(W1 @ perceive(xin) + b1))
__global__ __launch_bounds__(256) void nca_step(
    const float* __restrict__ xin, float* __restrict__ xout,
    const float* __restrict__ W1, const float* __restrict__ b1,
    const float* __restrict__ W2, uint32_t fk0, uint32_t fk1)
{
  __shared__ float xs[NCH][18][18];   // 25.9 KB halo tile

  const int tid = threadIdx.x;
  const int bx = blockIdx.x, by = blockIdx.y, bb = blockIdx.z;
  const int x0t = bx << 4, y0t = by << 4;
  const float* xb = xin + (size_t)bb * (NCH * HH * WW);

  // Stage 18x18 halo tile for all 20 channels, reflect padding at borders.
  for (int idx = tid; idx < NCH * 18 * 18; idx += 256) {
    int c  = idx / 324;
    int r  = idx - c * 324;
    int ly = r / 18;
    int lx = r - ly * 18;
    int gy = y0t + ly - 1;
    int gx = x0t + lx - 1;
    gy = (gy < 0) ? -gy : gy;  gy = (gy >= HH) ? (2 * HH - 2 - gy) : gy;
    gx = (gx < 0) ? -gx : gx;  gx = (gx >= WW) ? (2 * WW - 2 - gx) : gx;
    xs[c][ly][lx] = xb[c * (HH * WW) + gy * WW + gx];
  }
  __syncthreads();

  const int tx = tid & 15, ty = tid >> 4;

  // Perceive: p[0..19]=center, p[20+2c]=sobel_x, p[21+2c]=sobel_y
  float p[3 * NCH];
#pragma unroll
  for (int c = 0; c < NCH; ++c) {
    float a00 = xs[c][ty    ][tx    ], a01 = xs[c][ty    ][tx + 1], a02 = xs[c][ty    ][tx + 2];
    float a10 = xs[c][ty + 1][tx    ], a11 = xs[c][ty + 1][tx + 1], a12 = xs[c][ty + 1][tx + 2];
    float a20 = xs[c][ty + 2][tx    ], a21 = xs[c][ty + 2][tx + 1], a22 = xs[c][ty + 2][tx + 2];
    p[c] = a11;
    p[NCH + 2 * c    ] = ((a02 - a00) + 2.f * (a12 - a10) + (a22 - a20)) * 0.125f;
    p[NCH + 2 * c + 1] = ((a20 - a00) + 2.f * (a21 - a01) + (a22 - a02)) * 0.125f;
  }

  // Fused MLP: dx[c] = sum_k W2[c,k] * relu(b1[k] + sum_c W1[k,c] * p[c])
  float dxv[NCH];
#pragma unroll
  for (int c = 0; c < NCH; ++c) dxv[c] = 0.f;

  for (int k = 0; k < KH; ++k) {
    const float* w1r = W1 + k * 60;   // wave-uniform -> scalar loads
    float h0 = b1[k], h1 = 0.f, h2 = 0.f, h3 = 0.f;
#pragma unroll
    for (int c = 0; c < 60; c += 4) {
      h0 = fmaf(w1r[c    ], p[c    ], h0);
      h1 = fmaf(w1r[c + 1], p[c + 1], h1);
      h2 = fmaf(w1r[c + 2], p[c + 2], h2);
      h3 = fmaf(w1r[c + 3], p[c + 3], h3);
    }
    float hk = fmaxf((h0 + h1) + (h2 + h3), 0.f);
#pragma unroll
    for (int c = 0; c < NCH; ++c)
      dxv[c] = fmaf(W2[c * KH + k], hk, dxv[c]);
  }

  // Stochastic fire mask: JAX partitionable threefry (default since 0.5.0):
  // per flat index f of shape (B,1,H,W): counts = (hi=0, lo=f),
  // bits = out0 ^ out1 of one threefry block; u = bitcast((bits>>9)|1.0f)-1; fire = u<0.5
  uint32_t f = ((uint32_t)bb << 16) | ((uint32_t)(y0t + ty) << 8) | (uint32_t)(x0t + tx);
  uint32_t o0, o1;
  tf2x32(fk0, fk1, 0u, f, &o0, &o1);
  uint32_t bits = o0 ^ o1;
  float u = __uint_as_float((bits >> 9) | 0x3f800000u) - 1.0f;
  float fire = (u < 0.5f) ? 1.0f : 0.0f;

  size_t obase = (size_t)bb * (NCH * HH * WW) + (size_t)(y0t + ty) * WW + (x0t + tx);
#pragma unroll
  for (int c = 0; c < NCH; ++c) {
    float v = p[c];
    if (c >= 3) v = v + dxv[c] * fire;   // channels 0..2 immutable
    xout[obase + c * (HH * WW)] = v;
  }
}

extern "C" void kernel_launch(void* const* d_in, const int* in_sizes, int n_in,
                              void* d_out, int out_size, void* d_ws, size_t ws_size,
                              hipStream_t stream) {
  const float* x  = (const float*)d_in[0];
  const float* W1 = (const float*)d_in[1];
  const float* b1 = (const float*)d_in[2];
  const float* W2 = (const float*)d_in[3];
  const int steps = 64;   // fixed by setup_inputs()

  float* bufWs  = (float*)d_ws;   // 41.94 MB needed
  float* bufOut = (float*)d_out;

  dim3 grid(WW / 16, HH / 16, 8);
  dim3 block(256);

  const float* src = x;
  for (int s = 0; s < steps; ++s) {
    uint32_t fk0, fk1;
    tf2x32(0u, 42u, 0u, (uint32_t)s, &fk0, &fk1);   // fold_in(key(42), s)
    // parity chosen so the final step writes d_out; never in-place
    float* dst = ((steps - 1 - s) & 1) ? bufWs : bufOut;
    nca_step<<<grid, block, 0, stream>>>(src, dst, W1, b1, W2, fk0, fk1);
    src = dst;
  }
}

// Round 5
// 12482.827 us; speedup vs baseline: 1.0604x; 1.0604x over previous
//
#include <hip/hip_runtime.h>
#include <stdint.h>
#include <stddef.h>

#define HH 256
#define WW 256
#define NCH 20
#define KH 128
#define TSX 16
#define TSY 32
#define HALO_W 18
#define HALO_H 34

// JAX threefry2x32 (20 rounds), exact.
__host__ __device__ inline void tf2x32(uint32_t k0, uint32_t k1,
                                       uint32_t x0, uint32_t x1,
                                       uint32_t* o0, uint32_t* o1) {
  uint32_t ks0 = k0, ks1 = k1, ks2 = k0 ^ k1 ^ 0x1BD11BDAu;
  x0 += ks0; x1 += ks1;
#define RND(r) { x0 += x1; x1 = (x1 << (r)) | (x1 >> (32 - (r))); x1 ^= x0; }
  RND(13) RND(15) RND(26) RND(6)   x0 += ks1; x1 += ks2 + 1u;
  RND(17) RND(29) RND(16) RND(24)  x0 += ks2; x1 += ks0 + 2u;
  RND(13) RND(15) RND(26) RND(6)   x0 += ks0; x1 += ks1 + 3u;
  RND(17) RND(29) RND(16) RND(24)  x0 += ks1; x1 += ks2 + 4u;
  RND(13) RND(15) RND(26) RND(6)   x0 += ks2; x1 += ks0 + 5u;
#undef RND
  *o0 = x0; *o1 = x1;
}

__device__ inline float fire_of(uint32_t fk0, uint32_t fk1, uint32_t f) {
  // JAX partitionable threefry: counts hi=0, lo=f; bits = o0 ^ o1
  uint32_t o0, o1;
  tf2x32(fk0, fk1, 0u, f, &o0, &o1);
  uint32_t bits = o0 ^ o1;
  float u = __uint_as_float((bits >> 9) | 0x3f800000u) - 1.0f;
  return (u < 0.5f) ? 1.0f : 0.0f;
}

// One NCA step; each thread computes TWO vertically-adjacent pixels.
// __launch_bounds__(256,2): 2 waves/SIMD -> 256-VGPR budget, p[] stays in VGPRs.
__global__ __launch_bounds__(256, 2) void nca_step(
    const float* __restrict__ xin, float* __restrict__ xout,
    const float* __restrict__ W1, const float* __restrict__ b1,
    const float* __restrict__ W2, uint32_t fk0, uint32_t fk1)
{
  __shared__ float xs[NCH][HALO_H][HALO_W];  // 48.96 KB halo tile (16x32 px + 1 halo)
  __shared__ float w2b[KH][24];              // 12.3 KB: [k][0..19] = W2[c][k], [k][20] = b1[k]

  const int tid = threadIdx.x;
  const int bx = blockIdx.x, by = blockIdx.y, bb = blockIdx.z;
  const int x0t = bx * TSX, y0t = by * TSY;
  const float* xb = xin + (size_t)bb * (NCH * HH * WW);

  // ---- stage halo tile (reflect padding) ----
  for (int idx = tid; idx < NCH * HALO_H * HALO_W; idx += 256) {
    int c  = idx / (HALO_H * HALO_W);
    int r  = idx - c * (HALO_H * HALO_W);
    int ly = r / HALO_W;
    int lx = r - ly * HALO_W;
    int gy = y0t + ly - 1;
    int gx = x0t + lx - 1;
    gy = (gy < 0) ? -gy : gy;  gy = (gy >= HH) ? (2 * HH - 2 - gy) : gy;
    gx = (gx < 0) ? -gx : gx;  gx = (gx >= WW) ? (2 * WW - 2 - gx) : gx;
    xs[c][ly][lx] = xb[c * (HH * WW) + gy * WW + gx];
  }
  // ---- stage W2^T + b1 into LDS (broadcast-read later, kills scattered s_loads) ----
  for (int idx = tid; idx < KH * 21; idx += 256) {
    int k = idx / 21, c = idx - k * 21;
    w2b[k][c] = (c < 20) ? W2[c * KH + k] : b1[k];
  }
  __syncthreads();

  const int tx = tid & 15, tyy = tid >> 4;
  const int r0 = 2 * tyy;               // pixel rows r0, r0+1 in the 32-row tile
  // px row r taps lds rows r..r+2 (lds row = px row + 1 - 1 halo shift)

  // ---- perceive for both pixels; tap rows r0..r0+3 shared ----
  float pA[60], pB[60];
#pragma unroll
  for (int c = 0; c < NCH; ++c) {
    float t00 = xs[c][r0    ][tx], t01 = xs[c][r0    ][tx + 1], t02 = xs[c][r0    ][tx + 2];
    float t10 = xs[c][r0 + 1][tx], t11 = xs[c][r0 + 1][tx + 1], t12 = xs[c][r0 + 1][tx + 2];
    float t20 = xs[c][r0 + 2][tx], t21 = xs[c][r0 + 2][tx + 1], t22 = xs[c][r0 + 2][tx + 2];
    float t30 = xs[c][r0 + 3][tx], t31 = xs[c][r0 + 3][tx + 1], t32 = xs[c][r0 + 3][tx + 2];
    pA[c] = t11;
    pB[c] = t21;
    pA[NCH + 2 * c    ] = ((t02 - t00) + 2.f * (t12 - t10) + (t22 - t20)) * 0.125f;
    pA[NCH + 2 * c + 1] = ((t20 - t00) + 2.f * (t21 - t01) + (t22 - t02)) * 0.125f;
    pB[NCH + 2 * c    ] = ((t12 - t10) + 2.f * (t22 - t20) + (t32 - t30)) * 0.125f;
    pB[NCH + 2 * c + 1] = ((t30 - t10) + 2.f * (t31 - t11) + (t32 - t12)) * 0.125f;
  }

  float dxA[NCH], dxB[NCH];
#pragma unroll
  for (int c = 0; c < NCH; ++c) { dxA[c] = 0.f; dxB[c] = 0.f; }

  // ---- fused MLP over 128 hidden units, 2 pixels per thread ----
#pragma unroll 1
  for (int k = 0; k < KH; ++k) {
    const float* w1r = W1 + k * 60;        // uniform -> s_load_dwordx16 batches
    // broadcast ds_reads (uniform address, conflict-free)
    float4 wv0 = *(const float4*)&w2b[k][0];
    float4 wv1 = *(const float4*)&w2b[k][4];
    float4 wv2 = *(const float4*)&w2b[k][8];
    float4 wv3 = *(const float4*)&w2b[k][12];
    float4 wv4 = *(const float4*)&w2b[k][16];
    float  bk  = w2b[k][20];

    float a0 = bk, a1 = 0.f, a2 = 0.f, a3 = 0.f;
    float c0 = bk, c1 = 0.f, c2 = 0.f, c3 = 0.f;
#pragma unroll
    for (int c = 0; c < 60; c += 4) {
      float w0 = w1r[c], w1v = w1r[c + 1], w2v = w1r[c + 2], w3v = w1r[c + 3];
      a0 = fmaf(w0,  pA[c    ], a0);
      a1 = fmaf(w1v, pA[c + 1], a1);
      a2 = fmaf(w2v, pA[c + 2], a2);
      a3 = fmaf(w3v, pA[c + 3], a3);
      c0 = fmaf(w0,  pB[c    ], c0);
      c1 = fmaf(w1v, pB[c + 1], c1);
      c2 = fmaf(w2v, pB[c + 2], c2);
      c3 = fmaf(w3v, pB[c + 3], c3);
    }
    float hA = fmaxf((a0 + a1) + (a2 + a3), 0.f);
    float hB = fmaxf((c0 + c1) + (c2 + c3), 0.f);

    float w2arr[20] = { wv0.x, wv0.y, wv0.z, wv0.w,  wv1.x, wv1.y, wv1.z, wv1.w,
                        wv2.x, wv2.y, wv2.z, wv2.w,  wv3.x, wv3.y, wv3.z, wv3.w,
                        wv4.x, wv4.y, wv4.z, wv4.w };
#pragma unroll
    for (int c = 0; c < NCH; ++c) {
      dxA[c] = fmaf(w2arr[c], hA, dxA[c]);
      dxB[c] = fmaf(w2arr[c], hB, dxB[c]);
    }
  }

  // ---- stochastic fire masks (exact JAX partitionable threefry) ----
  const int gyA = y0t + r0, gyB = gyA + 1, gx = x0t + tx;
  float fireA = fire_of(fk0, fk1, ((uint32_t)bb << 16) | ((uint32_t)gyA << 8) | (uint32_t)gx);
  float fireB = fire_of(fk0, fk1, ((uint32_t)bb << 16) | ((uint32_t)gyB << 8) | (uint32_t)gx);

  size_t baseA = (size_t)bb * (NCH * HH * WW) + (size_t)gyA * WW + gx;
#pragma unroll
  for (int c = 0; c < NCH; ++c) {
    float vA = pA[c], vB = pB[c];
    if (c >= 3) { vA = vA + dxA[c] * fireA; vB = vB + dxB[c] * fireB; }
    xout[baseA + (size_t)c * (HH * WW)]      = vA;
    xout[baseA + (size_t)c * (HH * WW) + WW] = vB;
  }
}

extern "C" void kernel_launch(void* const* d_in, const int* in_sizes, int n_in,
                              void* d_out, int out_size, void* d_ws, size_t ws_size,
                              hipStream_t stream) {
  const float* x  = (const float*)d_in[0];
  const float* W1 = (const float*)d_in[1];
  const float* b1 = (const float*)d_in[2];
  const float* W2 = (const float*)d_in[3];
  const int steps = 64;   // fixed by setup_inputs()

  float* bufWs  = (float*)d_ws;   // ping buffer, 41.94 MB
  float* bufOut = (float*)d_out;

  dim3 grid(WW / TSX, HH / TSY, 8);
  dim3 block(256);

  const float* src = x;
  for (int s = 0; s < steps; ++s) {
    uint32_t fk0, fk1;
    tf2x32(0u, 42u, 0u, (uint32_t)s, &fk0, &fk1);   // fold_in(key(42), s)
    float* dst = ((steps - 1 - s) & 1) ? bufWs : bufOut;  // final step -> d_out
    nca_step<<<grid, block, 0, stream>>>(src, dst, W1, b1, W2, fk0, fk1);
    src = dst;
  }
}

// Round 6
// 11325.203 us; speedup vs baseline: 1.1688x; 1.1022x over previous
//
#include <hip/hip_runtime.h>
#include <stdint.h>
#include <stddef.h>

#define HH 256
#define WW 256
#define NCH 20
#define KH 128
#define TSX 16
#define TSY 32
#define HALO_W 18
#define HALO_H 34

// JAX threefry2x32 (20 rounds), exact.
__host__ __device__ inline void tf2x32(uint32_t k0, uint32_t k1,
                                       uint32_t x0, uint32_t x1,
                                       uint32_t* o0, uint32_t* o1) {
  uint32_t ks0 = k0, ks1 = k1, ks2 = k0 ^ k1 ^ 0x1BD11BDAu;
  x0 += ks0; x1 += ks1;
#define RND(r) { x0 += x1; x1 = (x1 << (r)) | (x1 >> (32 - (r))); x1 ^= x0; }
  RND(13) RND(15) RND(26) RND(6)   x0 += ks1; x1 += ks2 + 1u;
  RND(17) RND(29) RND(16) RND(24)  x0 += ks2; x1 += ks0 + 2u;
  RND(13) RND(15) RND(26) RND(6)   x0 += ks0; x1 += ks1 + 3u;
  RND(17) RND(29) RND(16) RND(24)  x0 += ks1; x1 += ks2 + 4u;
  RND(13) RND(15) RND(26) RND(6)   x0 += ks2; x1 += ks0 + 5u;
#undef RND
  *o0 = x0; *o1 = x1;
}

__device__ inline float fire_of(uint32_t fk0, uint32_t fk1, uint32_t f) {
  // JAX partitionable threefry: counts hi=0, lo=f; bits = o0 ^ o1
  uint32_t o0, o1;
  tf2x32(fk0, fk1, 0u, f, &o0, &o1);
  uint32_t bits = o0 ^ o1;
  float u = __uint_as_float((bits >> 9) | 0x3f800000u) - 1.0f;
  return (u < 0.5f) ? 1.0f : 0.0f;
}

// One NCA step; each thread computes TWO vertically-adjacent pixels.
// W1 staged in LDS (uniform broadcast ds_reads); W2/b1 via s_load (fit 16KB K$).
__global__ __launch_bounds__(256, 2) void nca_step(
    const float* __restrict__ xin, float* __restrict__ xout,
    const float* __restrict__ W1, const float* __restrict__ b1,
    const float* __restrict__ W2, uint32_t fk0, uint32_t fk1)
{
  __shared__ float xs[NCH][HALO_H][HALO_W];  // 48.96 KB halo tile (16x32 px + 1 halo)
  __shared__ float w1s[KH * 60];             // 30.72 KB; row k at 240B offset (16B aligned)

  const int tid = threadIdx.x;
  const int bx = blockIdx.x, by = blockIdx.y, bb = blockIdx.z;
  const int x0t = bx * TSX, y0t = by * TSY;
  const float* xb = xin + (size_t)bb * (NCH * HH * WW);

  // ---- stage W1 into LDS (float4 coalesced; 1920 float4s) ----
  for (int i = tid; i < KH * 15; i += 256)
    ((float4*)w1s)[i] = ((const float4*)W1)[i];

  // ---- stage halo tile (reflect padding) ----
  for (int idx = tid; idx < NCH * HALO_H * HALO_W; idx += 256) {
    int c  = idx / (HALO_H * HALO_W);
    int r  = idx - c * (HALO_H * HALO_W);
    int ly = r / HALO_W;
    int lx = r - ly * HALO_W;
    int gy = y0t + ly - 1;
    int gx = x0t + lx - 1;
    gy = (gy < 0) ? -gy : gy;  gy = (gy >= HH) ? (2 * HH - 2 - gy) : gy;
    gx = (gx < 0) ? -gx : gx;  gx = (gx >= WW) ? (2 * WW - 2 - gx) : gx;
    xs[c][ly][lx] = xb[c * (HH * WW) + gy * WW + gx];
  }
  __syncthreads();

  const int tx = tid & 15, tyy = tid >> 4;
  const int r0 = 2 * tyy;               // pixel rows r0, r0+1 of the 32-row tile

  // ---- perceive for both pixels; tap rows r0..r0+3 shared ----
  float pA[60], pB[60];
#pragma unroll
  for (int c = 0; c < NCH; ++c) {
    float t00 = xs[c][r0    ][tx], t01 = xs[c][r0    ][tx + 1], t02 = xs[c][r0    ][tx + 2];
    float t10 = xs[c][r0 + 1][tx], t11 = xs[c][r0 + 1][tx + 1], t12 = xs[c][r0 + 1][tx + 2];
    float t20 = xs[c][r0 + 2][tx], t21 = xs[c][r0 + 2][tx + 1], t22 = xs[c][r0 + 2][tx + 2];
    float t30 = xs[c][r0 + 3][tx], t31 = xs[c][r0 + 3][tx + 1], t32 = xs[c][r0 + 3][tx + 2];
    pA[c] = t11;
    pB[c] = t21;
    pA[NCH + 2 * c    ] = ((t02 - t00) + 2.f * (t12 - t10) + (t22 - t20)) * 0.125f;
    pA[NCH + 2 * c + 1] = ((t20 - t00) + 2.f * (t21 - t01) + (t22 - t02)) * 0.125f;
    pB[NCH + 2 * c    ] = ((t12 - t10) + 2.f * (t22 - t20) + (t32 - t30)) * 0.125f;
    pB[NCH + 2 * c + 1] = ((t30 - t10) + 2.f * (t31 - t11) + (t32 - t12)) * 0.125f;
  }

  // dx only for mutable channels 3..19 (0..2 are discarded by chan_mask)
  float dxA[17], dxB[17];
#pragma unroll
  for (int c = 0; c < 17; ++c) { dxA[c] = 0.f; dxB[c] = 0.f; }

  // ---- fused MLP over 128 hidden units, 2 pixels per thread ----
#pragma unroll 1
  for (int k = 0; k < KH; ++k) {
    const float bk = b1[k];              // s_load, 512B -> K$-hot
    float a0 = bk, a1 = 0.f, a2 = 0.f, a3 = 0.f;
    float c0 = bk, c1 = 0.f, c2 = 0.f, c3 = 0.f;
#pragma unroll
    for (int c = 0; c < 60; c += 4) {
      float4 w = *(const float4*)&w1s[k * 60 + c];   // uniform broadcast ds_read_b128
      a0 = fmaf(w.x, pA[c    ], a0);
      a1 = fmaf(w.y, pA[c + 1], a1);
      a2 = fmaf(w.z, pA[c + 2], a2);
      a3 = fmaf(w.w, pA[c + 3], a3);
      c0 = fmaf(w.x, pB[c    ], c0);
      c1 = fmaf(w.y, pB[c + 1], c1);
      c2 = fmaf(w.z, pB[c + 2], c2);
      c3 = fmaf(w.w, pB[c + 3], c3);
    }
    float hA = fmaxf((a0 + a1) + (a2 + a3), 0.f);
    float hB = fmaxf((c0 + c1) + (c2 + c3), 0.f);

#pragma unroll
    for (int c = 3; c < NCH; ++c) {
      float w2ck = W2[c * KH + k];       // s_load, 10.2KB -> K$-hot after 1st k
      dxA[c - 3] = fmaf(w2ck, hA, dxA[c - 3]);
      dxB[c - 3] = fmaf(w2ck, hB, dxB[c - 3]);
    }
  }

  // ---- stochastic fire masks (exact JAX partitionable threefry) ----
  const int gyA = y0t + r0, gyB = gyA + 1, gx = x0t + tx;
  float fireA = fire_of(fk0, fk1, ((uint32_t)bb << 16) | ((uint32_t)gyA << 8) | (uint32_t)gx);
  float fireB = fire_of(fk0, fk1, ((uint32_t)bb << 16) | ((uint32_t)gyB << 8) | (uint32_t)gx);

  size_t baseA = (size_t)bb * (NCH * HH * WW) + (size_t)gyA * WW + gx;
#pragma unroll
  for (int c = 0; c < NCH; ++c) {
    float vA = pA[c], vB = pB[c];
    if (c >= 3) { vA = vA + dxA[c - 3] * fireA; vB = vB + dxB[c - 3] * fireB; }
    xout[baseA + (size_t)c * (HH * WW)]      = vA;
    xout[baseA + (size_t)c * (HH * WW) + WW] = vB;
  }
}

extern "C" void kernel_launch(void* const* d_in, const int* in_sizes, int n_in,
                              void* d_out, int out_size, void* d_ws, size_t ws_size,
                              hipStream_t stream) {
  const float* x  = (const float*)d_in[0];
  const float* W1 = (const float*)d_in[1];
  const float* b1 = (const float*)d_in[2];
  const float* W2 = (const float*)d_in[3];
  const int steps = 64;   // fixed by setup_inputs()

  float* bufWs  = (float*)d_ws;   // ping buffer, 41.94 MB
  float* bufOut = (float*)d_out;

  dim3 grid(WW / TSX, HH / TSY, 8);
  dim3 block(256);

  const float* src = x;
  for (int s = 0; s < steps; ++s) {
    uint32_t fk0, fk1;
    tf2x32(0u, 42u, 0u, (uint32_t)s, &fk0, &fk1);   // fold_in(key(42), s)
    float* dst = ((steps - 1 - s) & 1) ? bufWs : bufOut;  // final step -> d_out
    nca_step<<<grid, block, 0, stream>>>(src, dst, W1, b1, W2, fk0, fk1);
    src = dst;
  }
}

// Round 8
// 11323.429 us; speedup vs baseline: 1.1690x; 1.0002x over previous
//
#include <hip/hip_runtime.h>
#include <stdint.h>
#include <stddef.h>

#define HH 256
#define WW 256
#define NCH 20
#define KH 128
#define TSX 16
#define TSY 32
#define HALO_W 18
#define HALO_H 34

// JAX threefry2x32 (20 rounds), exact.
__host__ __device__ inline void tf2x32(uint32_t k0, uint32_t k1,
                                       uint32_t x0, uint32_t x1,
                                       uint32_t* o0, uint32_t* o1) {
  uint32_t ks0 = k0, ks1 = k1, ks2 = k0 ^ k1 ^ 0x1BD11BDAu;
  x0 += ks0; x1 += ks1;
#define RND(r) { x0 += x1; x1 = (x1 << (r)) | (x1 >> (32 - (r))); x1 ^= x0; }
  RND(13) RND(15) RND(26) RND(6)   x0 += ks1; x1 += ks2 + 1u;
  RND(17) RND(29) RND(16) RND(24)  x0 += ks2; x1 += ks0 + 2u;
  RND(13) RND(15) RND(26) RND(6)   x0 += ks0; x1 += ks1 + 3u;
  RND(17) RND(29) RND(16) RND(24)  x0 += ks1; x1 += ks2 + 4u;
  RND(13) RND(15) RND(26) RND(6)   x0 += ks2; x1 += ks0 + 5u;
#undef RND
  *o0 = x0; *o1 = x1;
}

__device__ inline float fire_of(uint32_t fk0, uint32_t fk1, uint32_t f) {
  // JAX partitionable threefry: counts hi=0, lo=f; bits = o0 ^ o1
  uint32_t o0, o1;
  tf2x32(fk0, fk1, 0u, f, &o0, &o1);
  uint32_t bits = o0 ^ o1;
  float u = __uint_as_float((bits >> 9) | 0x3f800000u) - 1.0f;
  return (u < 0.5f) ? 1.0f : 0.0f;
}

// One NCA step; each thread computes TWO vertically-adjacent pixels.
// W1 staged in LDS (uniform broadcast ds_reads); W2/b1 via s_load (fit 16KB K$).
// waves_per_eu(2,2): pin occupancy target -> 256-VGPR budget, kill AGPR/scratch spill
// (live set ~190: pA[60]+pB[60]+dxA[17]+dxB[17]+temps; LDS already caps at 2 blocks/CU).
__global__ __attribute__((amdgpu_flat_work_group_size(256, 256), amdgpu_waves_per_eu(2, 2)))
void nca_step(
    const float* __restrict__ xin, float* __restrict__ xout,
    const float* __restrict__ W1, const float* __restrict__ b1,
    const float* __restrict__ W2, uint32_t fk0, uint32_t fk1)
{
  __shared__ float xs[NCH][HALO_H][HALO_W];  // 48.96 KB halo tile (16x32 px + 1 halo)
  __shared__ float w1s[KH * 60];             // 30.72 KB; row k at 240B offset (16B aligned)

  const int tid = threadIdx.x;
  const int bx = blockIdx.x, by = blockIdx.y, bb = blockIdx.z;
  const int x0t = bx * TSX, y0t = by * TSY;
  const float* xb = xin + (size_t)bb * (NCH * HH * WW);

  // ---- stage W1 into LDS (float4 coalesced; 1920 float4s) ----
  for (int i = tid; i < KH * 15; i += 256)
    ((float4*)w1s)[i] = ((const float4*)W1)[i];

  // ---- stage halo tile (reflect padding) ----
  for (int idx = tid; idx < NCH * HALO_H * HALO_W; idx += 256) {
    int c  = idx / (HALO_H * HALO_W);
    int r  = idx - c * (HALO_H * HALO_W);
    int ly = r / HALO_W;
    int lx = r - ly * HALO_W;
    int gy = y0t + ly - 1;
    int gx = x0t + lx - 1;
    gy = (gy < 0) ? -gy : gy;  gy = (gy >= HH) ? (2 * HH - 2 - gy) : gy;
    gx = (gx < 0) ? -gx : gx;  gx = (gx >= WW) ? (2 * WW - 2 - gx) : gx;
    xs[c][ly][lx] = xb[c * (HH * WW) + gy * WW + gx];
  }
  __syncthreads();

  const int tx = tid & 15, tyy = tid >> 4;
  const int r0 = 2 * tyy;               // pixel rows r0, r0+1 of the 32-row tile

  // ---- perceive for both pixels; tap rows r0..r0+3 shared ----
  float pA[60], pB[60];
#pragma unroll
  for (int c = 0; c < NCH; ++c) {
    float t00 = xs[c][r0    ][tx], t01 = xs[c][r0    ][tx + 1], t02 = xs[c][r0    ][tx + 2];
    float t10 = xs[c][r0 + 1][tx], t11 = xs[c][r0 + 1][tx + 1], t12 = xs[c][r0 + 1][tx + 2];
    float t20 = xs[c][r0 + 2][tx], t21 = xs[c][r0 + 2][tx + 1], t22 = xs[c][r0 + 2][tx + 2];
    float t30 = xs[c][r0 + 3][tx], t31 = xs[c][r0 + 3][tx + 1], t32 = xs[c][r0 + 3][tx + 2];
    pA[c] = t11;
    pB[c] = t21;
    pA[NCH + 2 * c    ] = ((t02 - t00) + 2.f * (t12 - t10) + (t22 - t20)) * 0.125f;
    pA[NCH + 2 * c + 1] = ((t20 - t00) + 2.f * (t21 - t01) + (t22 - t02)) * 0.125f;
    pB[NCH + 2 * c    ] = ((t12 - t10) + 2.f * (t22 - t20) + (t32 - t30)) * 0.125f;
    pB[NCH + 2 * c + 1] = ((t30 - t10) + 2.f * (t31 - t11) + (t32 - t12)) * 0.125f;
  }

  // dx only for mutable channels 3..19 (0..2 are discarded by chan_mask)
  float dxA[17], dxB[17];
#pragma unroll
  for (int c = 0; c < 17; ++c) { dxA[c] = 0.f; dxB[c] = 0.f; }

  // ---- fused MLP over 128 hidden units, 2 pixels per thread ----
#pragma unroll 1
  for (int k = 0; k < KH; ++k) {
    const float bk = b1[k];              // s_load, 512B -> K$-hot
    float a0 = bk, a1 = 0.f, a2 = 0.f, a3 = 0.f;
    float c0 = bk, c1 = 0.f, c2 = 0.f, c3 = 0.f;
#pragma unroll
    for (int c = 0; c < 60; c += 4) {
      float4 w = *(const float4*)&w1s[k * 60 + c];   // uniform broadcast ds_read_b128
      a0 = fmaf(w.x, pA[c    ], a0);
      a1 = fmaf(w.y, pA[c + 1], a1);
      a2 = fmaf(w.z, pA[c + 2], a2);
      a3 = fmaf(w.w, pA[c + 3], a3);
      c0 = fmaf(w.x, pB[c    ], c0);
      c1 = fmaf(w.y, pB[c + 1], c1);
      c2 = fmaf(w.z, pB[c + 2], c2);
      c3 = fmaf(w.w, pB[c + 3], c3);
    }
    float hA = fmaxf((a0 + a1) + (a2 + a3), 0.f);
    float hB = fmaxf((c0 + c1) + (c2 + c3), 0.f);

#pragma unroll
    for (int c = 3; c < NCH; ++c) {
      float w2ck = W2[c * KH + k];       // s_load, 10.2KB -> K$-hot after 1st k
      dxA[c - 3] = fmaf(w2ck, hA, dxA[c - 3]);
      dxB[c - 3] = fmaf(w2ck, hB, dxB[c - 3]);
    }
  }

  // ---- stochastic fire masks (exact JAX partitionable threefry) ----
  const int gyA = y0t + r0, gyB = gyA + 1, gx = x0t + tx;
  float fireA = fire_of(fk0, fk1, ((uint32_t)bb << 16) | ((uint32_t)gyA << 8) | (uint32_t)gx);
  float fireB = fire_of(fk0, fk1, ((uint32_t)bb << 16) | ((uint32_t)gyB << 8) | (uint32_t)gx);

  size_t baseA = (size_t)bb * (NCH * HH * WW) + (size_t)gyA * WW + gx;
#pragma unroll
  for (int c = 0; c < NCH; ++c) {
    float vA = pA[c], vB = pB[c];
    if (c >= 3) { vA = vA + dxA[c - 3] * fireA; vB = vB + dxB[c - 3] * fireB; }
    xout[baseA + (size_t)c * (HH * WW)]      = vA;
    xout[baseA + (size_t)c * (HH * WW) + WW] = vB;
  }
}

extern "C" void kernel_launch(void* const* d_in, const int* in_sizes, int n_in,
                              void* d_out, int out_size, void* d_ws, size_t ws_size,
                              hipStream_t stream) {
  const float* x  = (const float*)d_in[0];
  const float* W1 = (const float*)d_in[1];
  const float* b1 = (const float*)d_in[2];
  const float* W2 = (const float*)d_in[3];
  const int steps = 64;   // fixed by setup_inputs()

  float* bufWs  = (float*)d_ws;   // ping buffer, 41.94 MB
  float* bufOut = (float*)d_out;

  dim3 grid(WW / TSX, HH / TSY, 8);
  dim3 block(256);

  const float* src = x;
  for (int s = 0; s < steps; ++s) {
    uint32_t fk0, fk1;
    tf2x32(0u, 42u, 0u, (uint32_t)s, &fk0, &fk1);   // fold_in(key(42), s)
    float* dst = ((steps - 1 - s) & 1) ? bufWs : bufOut;  // final step -> d_out
    nca_step<<<grid, block, 0, stream>>>(src, dst, W1, b1, W2, fk0, fk1);
    src = dst;
  }
}